// Round 2
// baseline (281.994 us; speedup 1.0000x reference)
//
#include <hip/hip_runtime.h>

// quadLayer: B=8, H=W=64, C=16, K=S=2, FM=32 -> oh=ow=32, 8192 locations,
// 8192 fp32 outputs/location (268 MB). Memory-bound on the output write.
//
// out[loc*8192 + c*512 + a*32 + f] =
//   sum_m p[a,m]*W1[c,m,f] + sum_{m1,m2} p[a,m1]p[a,m2]*W2[c,m1*4+m2,f]
// = sum_{m1} p[a,m1] * ( W1[c,m1,f] + sum_{m2} p[a,m2]*W2[c,m1*4+m2,f] )
//
// Patch depth d=(ki*2+kj)*16+c16 reinterpreted as (a=d>>2, m=d&3), so
// pv(a)=p[a,0:4] is the contiguous float4 x[b,2h+ki,2w+kj,(a&3)*4 .. +4]
// with ki=a>>3, kj=(a>>2)&1. A thread's 8 a-values (fixed ki) are 32
// contiguous floats -> 8 L1-hit f4 loads, wave-uniform address.
// => no LDS, no barriers, weights held in 80 VGPRs per thread.

typedef float f4 __attribute__((ext_vector_type(4)));

#define LPB 4  // locations per block; 8192/4 = 2048 blocks

__global__ __launch_bounds__(256) void quad_kernel(
    const float* __restrict__ x,
    const float* __restrict__ W1,
    const float* __restrict__ W2,
    float* __restrict__ out)
{
    const int t     = threadIdx.x;
    const int f4off = (t & 7) * 4;      // f in {0,4,...,28}
    const int s     = t >> 3;           // 0..31
    const int c     = s & 15;           // output channel (fixed per thread)
    const int ki    = s >> 4;           // a-half: a = ki*8 + j  (wave-uniform)

    // weights for this (c, f4off): 20 float4 = 80 VGPRs, L2-resident loads
    f4 w1r[4], w2r[16];
    {
        const float* W1p = W1 + c * 128 + f4off;
#pragma unroll
        for (int m = 0; m < 4; ++m)  w1r[m] = *(const f4*)(W1p + m * 32);
        const float* W2p = W2 + c * 512 + f4off;
#pragma unroll
        for (int q = 0; q < 16; ++q) w2r[q] = *(const f4*)(W2p + q * 32);
    }

    const int loc0 = blockIdx.x * LPB;

#pragma unroll 1
    for (int i = 0; i < LPB; ++i) {
        const int loc = loc0 + i;
        const int b   = loc >> 10;
        const int hw  = loc & 1023;
        const int h   = hw >> 5;
        const int w   = hw & 31;

        // 32 contiguous floats: x[b, 2h+ki, 2w + (0|1), 0:16]
        const float* px = x + (((b * 64 + 2 * h + ki) * 64) + 2 * w) * 16;
        float* outp = out + (size_t)loc * 8192 + c * 512 + ki * 256 + f4off;

        f4 pvs[8];
#pragma unroll
        for (int j = 0; j < 8; ++j)
            pvs[j] = *(const f4*)(px + j * 4);

#pragma unroll
        for (int j = 0; j < 8; ++j) {
            const f4 pv = pvs[j];
            f4 t0 = w1r[0], t1 = w1r[1], t2 = w1r[2], t3 = w1r[3];
            t0 += pv.x * w2r[0];   t0 += pv.y * w2r[1];
            t0 += pv.z * w2r[2];   t0 += pv.w * w2r[3];
            t1 += pv.x * w2r[4];   t1 += pv.y * w2r[5];
            t1 += pv.z * w2r[6];   t1 += pv.w * w2r[7];
            t2 += pv.x * w2r[8];   t2 += pv.y * w2r[9];
            t2 += pv.z * w2r[10];  t2 += pv.w * w2r[11];
            t3 += pv.x * w2r[12];  t3 += pv.y * w2r[13];
            t3 += pv.z * w2r[14];  t3 += pv.w * w2r[15];

            f4 acc = pv.x * t0;
            acc += pv.y * t1;
            acc += pv.z * t2;
            acc += pv.w * t3;

            // a = ki*8 + j  ->  offset a*32 = ki*256 (in outp) + j*32
            __builtin_nontemporal_store(acc, (f4*)(outp + j * 32));
        }
    }
}

extern "C" void kernel_launch(void* const* d_in, const int* in_sizes, int n_in,
                              void* d_out, int out_size, void* d_ws, size_t ws_size,
                              hipStream_t stream) {
    const float* x  = (const float*)d_in[0];   // [8,64,64,16]
    const float* W1 = (const float*)d_in[1];   // [16,4,32]
    const float* W2 = (const float*)d_in[2];   // [16,16,32]
    float* out = (float*)d_out;                // [8,32,32,8192]

    const int n_loc = 8 * 32 * 32;             // 8192
    dim3 grid(n_loc / LPB), block(256);
    quad_kernel<<<grid, block, 0, stream>>>(x, W1, W2, out);
}